// Round 2
// baseline (317.637 us; speedup 1.0000x reference)
//
#include <hip/hip_runtime.h>

#define NSITES 32768
#define SPB 16                    // sites per block
#define THREADS 192               // 3 waves; 192 = 16 sites x 12 rows
#define DIAG 4.5f
#define VSTRIDE 100               // psi LDS row stride (floats); 400B keeps float4 alignment
#define MU_STRIDE (NSITES*144)

typedef float f4 __attribute__((ext_vector_type(4)));

__device__ __forceinline__ void cdot4(const f4 kr, const f4 ki,
                                      const f4 vr, const f4 vi,
                                      float& sr, float& si) {
    sr = fmaf(kr.x, vr.x, sr); sr = fmaf(-ki.x, vi.x, sr);
    si = fmaf(kr.x, vi.x, si); si = fmaf(ki.x, vr.x, si);
    sr = fmaf(kr.y, vr.y, sr); sr = fmaf(-ki.y, vi.y, sr);
    si = fmaf(kr.y, vi.y, si); si = fmaf(ki.y, vr.y, si);
    sr = fmaf(kr.z, vr.z, sr); sr = fmaf(-ki.z, vi.z, sr);
    si = fmaf(kr.z, vi.z, si); si = fmaf(ki.z, vr.z, si);
    sr = fmaf(kr.w, vr.w, sr); sr = fmaf(-ki.w, vi.w, sr);
    si = fmaf(kr.w, vi.w, si); si = fmaf(ki.w, vr.w, si);
}

// K path: registers, TRIPLE-buffered (18 float4 = 72 VGPR), loads pinned in
// place with sched_barrier(0) so the compiler cannot sink them to their uses
// (round-1 post-mortem: VGPR=44 proved the double-buffer was destroyed).
// K has zero reuse -> non-temporal loads (no L2/L3 fill churn; psi keeps its
// 9x-reuse lines cached). Output is write-once -> non-temporal store.
__global__ __launch_bounds__(THREADS, 4) void hop_kernel(
    const float* __restrict__ psi_re, const float* __restrict__ psi_im,
    const float* __restrict__ K_fwd_re, const float* __restrict__ K_fwd_im,
    const float* __restrict__ K_bwd_re, const float* __restrict__ K_bwd_im,
    float* __restrict__ out_re, float* __restrict__ out_im)
{
    __shared__ alignas(16) float vre[SPB][VSTRIDE];              // 6400B
    __shared__ alignas(16) float vim[SPB][VSTRIDE];              // 6400B

    const int tid   = threadIdx.x;
    const int site0 = blockIdx.x * SPB;

    // ---- psi staging (unchanged from verified kernel) ----
    const int jj  = tid % 12;
    const int scb = tid / 12;
    const int cc  = scb & 7;
    const int sb  = scb >> 3;
    const int dt = (cc == 0) - (cc == 1);
    const int dz = (cc == 2) - (cc == 3);
    const int dy = (cc == 4) - (cc == 5);

    float tr[8], ti[8];
    int   dst[8];
    #pragma unroll
    for (int k = 0; k < 8; ++k) {
        const int s2 = sb + 2 * k;
        const int sg = site0 + s2;
        const int x = sg & 7, y = (sg >> 3) & 15, z = (sg >> 7) & 15, t = (sg >> 11) & 15;
        const int r = (t + z + y) & 1;                 // OUT_PARITY = 0
        int dx = 0;
        if (cc == 6) dx =  (r == 1);                   // X fwd where mask_f
        if (cc == 7) dx = -(r == 0);                   // X bwd where mask_b
        const int nt = (t + dt) & 15, nz = (z + dz) & 15,
                  ny = (y + dy) & 15, nx = (x + dx) & 7;
        const int n = ((nt * 16 + nz) * 16 + ny) * 8 + nx;
        tr[k]  = psi_re[n * 12 + jj];
        ti[k]  = psi_im[n * 12 + jj];
        dst[k] = s2 * VSTRIDE + cc * 12 + jj;
    }

    // center psi (coalesced: site*12 + jj == site0*12 + tid)
    const int s    = scb;          // compute-phase local site
    const int site = site0 + s;
    const float pr_c = psi_re[site * 12 + jj];
    const float pi_c = psi_im[site * 12 + jj];

    #pragma unroll
    for (int k = 0; k < 8; ++k) {
        ((float*)vre)[dst[k]] = tr[k];
        ((float*)vim)[dst[k]] = ti[k];
    }

    // per-thread K row base (floats): site*144 + row*12 == site0*144 + tid*12
    const int goff = site0 * 144 + tid * 12;

    // triple buffer: X, Y, Z
    f4 x0, x1, x2, x3, x4, x5;
    f4 y0, y1, y2, y3, y4, y5;
    f4 z0, z1, z2, z3, z4, z5;

#define LOADC(c, R0, R1, R2, I0, I1, I2) do { \
    const float* _kr = (((c) & 1) ? K_bwd_re : K_fwd_re) + ((c) >> 1) * MU_STRIDE + goff; \
    const float* _ki = (((c) & 1) ? K_bwd_im : K_fwd_im) + ((c) >> 1) * MU_STRIDE + goff; \
    R0 = __builtin_nontemporal_load((const f4*)_kr + 0); \
    R1 = __builtin_nontemporal_load((const f4*)_kr + 1); \
    R2 = __builtin_nontemporal_load((const f4*)_kr + 2); \
    I0 = __builtin_nontemporal_load((const f4*)_ki + 0); \
    I1 = __builtin_nontemporal_load((const f4*)_ki + 1); \
    I2 = __builtin_nontemporal_load((const f4*)_ki + 2); \
    __builtin_amdgcn_sched_barrier(0); /* pin: loads may not sink below here */ \
} while (0)

#define COMPUTE(c, R0, R1, R2, I0, I1, I2) do { \
    const f4 vr0 = *(const f4*)&vre[s][(c) * 12 + 0]; \
    const f4 vr1 = *(const f4*)&vre[s][(c) * 12 + 4]; \
    const f4 vr2 = *(const f4*)&vre[s][(c) * 12 + 8]; \
    const f4 vi0 = *(const f4*)&vim[s][(c) * 12 + 0]; \
    const f4 vi1 = *(const f4*)&vim[s][(c) * 12 + 4]; \
    const f4 vi2 = *(const f4*)&vim[s][(c) * 12 + 8]; \
    float sr = 0.f, si = 0.f; \
    cdot4(R0, I0, vr0, vi0, sr, si); \
    cdot4(R1, I1, vr1, vi1, sr, si); \
    cdot4(R2, I2, vr2, vi2, sr, si); \
    o_re -= 0.5f * sr; \
    o_im -= 0.5f * si; \
} while (0)

    // prefetch c=0,1 before the barrier: latency drains with the staging loads
    LOADC(0, x0, x1, x2, x3, x4, x5);
    LOADC(1, y0, y1, y2, y3, y4, y5);

    __syncthreads();               // staging writes visible

    float o_re = DIAG * pr_c;
    float o_im = DIAG * pi_c;

    // steady state: every load issued 2 compute-phases (~800 cyc) before use
    LOADC(2, z0, z1, z2, z3, z4, z5);
    COMPUTE(0, x0, x1, x2, x3, x4, x5);  LOADC(3, x0, x1, x2, x3, x4, x5);
    COMPUTE(1, y0, y1, y2, y3, y4, y5);  LOADC(4, y0, y1, y2, y3, y4, y5);
    COMPUTE(2, z0, z1, z2, z3, z4, z5);  LOADC(5, z0, z1, z2, z3, z4, z5);
    COMPUTE(3, x0, x1, x2, x3, x4, x5);  LOADC(6, x0, x1, x2, x3, x4, x5);
    COMPUTE(4, y0, y1, y2, y3, y4, y5);  LOADC(7, y0, y1, y2, y3, y4, y5);
    COMPUTE(5, z0, z1, z2, z3, z4, z5);
    COMPUTE(6, x0, x1, x2, x3, x4, x5);
    COMPUTE(7, y0, y1, y2, y3, y4, y5);

#undef LOADC
#undef COMPUTE

    __builtin_nontemporal_store(o_re, &out_re[site * 12 + jj]);   // coalesced
    __builtin_nontemporal_store(o_im, &out_im[site * 12 + jj]);
}

extern "C" void kernel_launch(void* const* d_in, const int* in_sizes, int n_in,
                              void* d_out, int out_size, void* d_ws, size_t ws_size,
                              hipStream_t stream) {
    const float* psi_re   = (const float*)d_in[0];
    const float* psi_im   = (const float*)d_in[1];
    const float* K_fwd_re = (const float*)d_in[2];
    const float* K_fwd_im = (const float*)d_in[3];
    const float* K_bwd_re = (const float*)d_in[4];
    const float* K_bwd_im = (const float*)d_in[5];
    float* out_re = (float*)d_out;
    float* out_im = out_re + (out_size / 2);    // NSITES*12 = 393216

    hop_kernel<<<NSITES / SPB, THREADS, 0, stream>>>(
        psi_re, psi_im, K_fwd_re, K_fwd_im, K_bwd_re, K_bwd_im, out_re, out_im);
}

// Round 4
// 276.817 us; speedup vs baseline: 1.1475x; 1.1475x over previous
//
#include <hip/hip_runtime.h>

#define NSITES 32768
#define SPB 16                    // sites per block
#define THREADS 192               // 3 waves; 192 = 16 sites x 12 rows
#define DIAG 4.5f
#define VSTRIDE 100               // psi LDS row stride (floats); 400B keeps float4 alignment
#define MU_STRIDE (NSITES*144)

typedef float f4 __attribute__((ext_vector_type(4)));

__device__ __forceinline__ void cdot4(const f4 kr, const f4 ki,
                                      const f4 vr, const f4 vi,
                                      float& sr, float& si) {
    sr = fmaf(kr.x, vr.x, sr); sr = fmaf(-ki.x, vi.x, sr);
    si = fmaf(kr.x, vi.x, si); si = fmaf(ki.x, vr.x, si);
    sr = fmaf(kr.y, vr.y, sr); sr = fmaf(-ki.y, vi.y, sr);
    si = fmaf(kr.y, vi.y, si); si = fmaf(ki.y, vr.y, si);
    sr = fmaf(kr.z, vr.z, sr); sr = fmaf(-ki.z, vi.z, sr);
    si = fmaf(kr.z, vi.z, si); si = fmaf(ki.z, vr.z, si);
    sr = fmaf(kr.w, vr.w, sr); sr = fmaf(-ki.w, vi.w, sr);
    si = fmaf(kr.w, vi.w, si); si = fmaf(ki.w, vr.w, si);
}

// Opaque asm loads: hipcc cannot sink/merge them (R1 VGPR=44, R2 VGPR=64
// proved it flattens every compiler-visible register pipeline).
// "=&v" early-clobber: dest quad may never alias the live address pair.
#define GLOAD(dst, ptr, IMM) \
    asm volatile("global_load_dwordx4 %0, %1, off offset:" #IMM \
                 : "=&v"(dst) : "v"(ptr))

#define LOADC(c, R0, R1, R2, I0, I1, I2) do { \
    const float* _kr = (((c) & 1) ? K_bwd_re : K_fwd_re) + ((c) >> 1) * MU_STRIDE + goff; \
    const float* _ki = (((c) & 1) ? K_bwd_im : K_fwd_im) + ((c) >> 1) * MU_STRIDE + goff; \
    GLOAD(R0, _kr, 0); GLOAD(R1, _kr, 16); GLOAD(R2, _kr, 32); \
    GLOAD(I0, _ki, 0); GLOAD(I1, _ki, 16); GLOAD(I2, _ki, 32); \
} while (0)

// Counted wait + rule-18 fence. vmem returns are IN-ORDER, so any
// compiler-tracked loads mixed into the count only make this stronger.
#define KWAIT(N) do { \
    asm volatile("s_waitcnt vmcnt(" #N ")" ::: "memory"); \
    __builtin_amdgcn_sched_barrier(0); \
} while (0)

// launch_bounds(192,3): 3 waves/EU (12/CU, = R1's achieved occupancy) with
// VGPR headroom to 168 so the asm pipeline (72 VGPR of buffers) cannot spill.
__global__ __launch_bounds__(THREADS, 3) void hop_kernel(
    const float* __restrict__ psi_re, const float* __restrict__ psi_im,
    const float* __restrict__ K_fwd_re, const float* __restrict__ K_fwd_im,
    const float* __restrict__ K_bwd_re, const float* __restrict__ K_bwd_im,
    float* __restrict__ out_re, float* __restrict__ out_im)
{
    __shared__ alignas(16) float vre[SPB][VSTRIDE];              // 6400B
    __shared__ alignas(16) float vim[SPB][VSTRIDE];              // 6400B

    const int tid   = threadIdx.x;
    const int site0 = blockIdx.x * SPB;

    // ---- psi staging (unchanged from verified kernel) ----
    const int jj  = tid % 12;
    const int scb = tid / 12;
    const int cc  = scb & 7;
    const int sb  = scb >> 3;
    const int dt = (cc == 0) - (cc == 1);
    const int dz = (cc == 2) - (cc == 3);
    const int dy = (cc == 4) - (cc == 5);

    float tr[8], ti[8];
    int   dst[8];
    #pragma unroll
    for (int k = 0; k < 8; ++k) {
        const int s2 = sb + 2 * k;
        const int sg = site0 + s2;
        const int x = sg & 7, y = (sg >> 3) & 15, z = (sg >> 7) & 15, t = (sg >> 11) & 15;
        const int r = (t + z + y) & 1;                 // OUT_PARITY = 0
        int dx = 0;
        if (cc == 6) dx =  (r == 1);                   // X fwd where mask_f
        if (cc == 7) dx = -(r == 0);                   // X bwd where mask_b
        const int nt = (t + dt) & 15, nz = (z + dz) & 15,
                  ny = (y + dy) & 15, nx = (x + dx) & 7;
        const int n = ((nt * 16 + nz) * 16 + ny) * 8 + nx;
        tr[k]  = psi_re[n * 12 + jj];
        ti[k]  = psi_im[n * 12 + jj];
        dst[k] = s2 * VSTRIDE + cc * 12 + jj;
    }

    // center psi (coalesced: site*12 + jj == site0*12 + tid)
    const int s    = scb;          // compute-phase local site
    const int site = site0 + s;
    const float pr_c = psi_re[site * 12 + jj];
    const float pi_c = psi_im[site * 12 + jj];

    #pragma unroll
    for (int k = 0; k < 8; ++k) {
        ((float*)vre)[dst[k]] = tr[k];
        ((float*)vim)[dst[k]] = ti[k];
    }

    // per-thread K row base (floats): site*144 + row*12 == site0*144 + tid*12
    const int goff = site0 * 144 + tid * 12;

    // triple buffer X/Y/Z: 18 x f4 = 72 VGPR, held live by opaque asm defs
    f4 x0, x1, x2, x3, x4, x5;
    f4 y0, y1, y2, y3, y4, y5;
    f4 z0, z1, z2, z3, z4, z5;

#define COMPUTE(c, R0, R1, R2, I0, I1, I2) do { \
    const f4 vr0 = *(const f4*)&vre[s][(c) * 12 + 0]; \
    const f4 vr1 = *(const f4*)&vre[s][(c) * 12 + 4]; \
    const f4 vr2 = *(const f4*)&vre[s][(c) * 12 + 8]; \
    const f4 vi0 = *(const f4*)&vim[s][(c) * 12 + 0]; \
    const f4 vi1 = *(const f4*)&vim[s][(c) * 12 + 4]; \
    const f4 vi2 = *(const f4*)&vim[s][(c) * 12 + 8]; \
    float sr = 0.f, si = 0.f; \
    cdot4(R0, I0, vr0, vi0, sr, si); \
    cdot4(R1, I1, vr1, vi1, sr, si); \
    cdot4(R2, I2, vr2, vi2, sr, si); \
    o_re -= 0.5f * sr; \
    o_im -= 0.5f * si; \
} while (0)

    // prologue: c=0,1,2 in flight before the barrier (latency overlaps the
    // staging drain; if the barrier drains vmcnt the waits below pass early
    // and are still correct)
    LOADC(0, x0, x1, x2, x3, x4, x5);
    LOADC(1, y0, y1, y2, y3, y4, y5);
    LOADC(2, z0, z1, z2, z3, z4, z5);

    __syncthreads();               // staging writes visible

    float o_re = DIAG * pr_c;
    float o_im = DIAG * pi_c;

    // steady state: 18 dwordx4 in flight per wave, 2-phase lookahead
    KWAIT(12); COMPUTE(0, x0, x1, x2, x3, x4, x5); LOADC(3, x0, x1, x2, x3, x4, x5);
    KWAIT(12); COMPUTE(1, y0, y1, y2, y3, y4, y5); LOADC(4, y0, y1, y2, y3, y4, y5);
    KWAIT(12); COMPUTE(2, z0, z1, z2, z3, z4, z5); LOADC(5, z0, z1, z2, z3, z4, z5);
    KWAIT(12); COMPUTE(3, x0, x1, x2, x3, x4, x5); LOADC(6, x0, x1, x2, x3, x4, x5);
    KWAIT(12); COMPUTE(4, y0, y1, y2, y3, y4, y5); LOADC(7, y0, y1, y2, y3, y4, y5);
    KWAIT(12); COMPUTE(5, z0, z1, z2, z3, z4, z5);
    KWAIT(6);  COMPUTE(6, x0, x1, x2, x3, x4, x5);
    KWAIT(0);  COMPUTE(7, y0, y1, y2, y3, y4, y5);

#undef COMPUTE

    out_re[site * 12 + jj] = o_re;               // block*192 + tid: fully coalesced
    out_im[site * 12 + jj] = o_im;
}

extern "C" void kernel_launch(void* const* d_in, const int* in_sizes, int n_in,
                              void* d_out, int out_size, void* d_ws, size_t ws_size,
                              hipStream_t stream) {
    const float* psi_re   = (const float*)d_in[0];
    const float* psi_im   = (const float*)d_in[1];
    const float* K_fwd_re = (const float*)d_in[2];
    const float* K_fwd_im = (const float*)d_in[3];
    const float* K_bwd_re = (const float*)d_in[4];
    const float* K_bwd_im = (const float*)d_in[5];
    float* out_re = (float*)d_out;
    float* out_im = out_re + (out_size / 2);    // NSITES*12 = 393216

    hop_kernel<<<NSITES / SPB, THREADS, 0, stream>>>(
        psi_re, psi_im, K_fwd_re, K_fwd_im, K_bwd_re, K_bwd_im, out_re, out_im);
}